// Round 13
// baseline (131.084 us; speedup 1.0000x reference)
//
#include <hip/hip_runtime.h>
#include <hip/hip_bf16.h>
#include <math.h>

#define BD 8        // batch
#define TD 1024     // T
#define CD 1024     // C
#define PD 100      // patterns
#define KS 16       // K-split for hidden GEMMs
#define KW (CD / KS)   // 64
#define SEG 2048    // floats per out-block segment (8 KB)
#define TT (TD * TD)
#define SPLITQ 48   // planes q < SPLITQ load cacheable (as R11)
#define LAMBDA 0.1f
#define SIM_THR 0.5f

typedef float f4 __attribute__((ext_vector_type(4)));

// -------- device-global scratch (fully rewritten each call; deterministic) --
__device__ float    g_pctx[KS][BD][CD];   // k-partials of context hidden
__device__ float    g_ptrg[KS][PD][CD];   // k-partials of trigger hidden
__device__ float    g_ctxb[BD][CD];       // b1 + sum_kz pctx  (final)
__device__ float    g_trgh[PD][CD];       // sum_kz ptrg       (final)
__device__ float    g_wd[PD];             // dense gated weights, lambda folded
__device__ unsigned g_cnt[44];            // per-(x,y)-tile arrival counters
// NOTE: g_cnt is never reset; each call adds exactly 16 per counter, finisher
// is detected by (old & 15) == 15 -> identical behavior on every graph replay.

// -------- K1: partial hidden + last-finisher reduction ----------------------
// grid = (4, 11, KS): y==0 -> context (8 rows), y=1..10 -> trigger chunk.
// The 16th kz-block per (x,y) tile reduces the partials into g_ctxb/g_trgh.
__global__ __launch_bounds__(256) void hidden_kernel(const float* __restrict__ context,
                                                     const float* __restrict__ triggers,
                                                     const float* __restrict__ W1,
                                                     const float* __restrict__ b1) {
    const int c  = blockIdx.x * 256 + threadIdx.x;   // output column
    const int kz = blockIdx.z;
    const int k0 = kz * KW;
    const bool is_ctx = (blockIdx.y == 0);
    const int  ych = blockIdx.y - 1;                 // trigger chunk 0..9
    const float* __restrict__ W1p = is_ctx ? W1 : (W1 + (size_t)CD * CD);
    const float* __restrict__ src = is_ctx ? context : (triggers + (size_t)ych * 10 * CD);
    float* __restrict__ dst = is_ctx ? &g_pctx[kz][0][0] : &g_ptrg[kz][ych * 10][0];
    const int nrows = is_ctx ? 8 : 10;

    __shared__ float s_src[10][KW];
    __shared__ bool  s_last;
    for (int t = threadIdx.x; t < 10 * KW; t += 256) {
        const int r = t >> 6, k = t & (KW - 1);
        s_src[r][k] = src[(size_t)(r < nrows ? r : 0) * CD + k0 + k];
    }
    __syncthreads();

    float acc[10];
#pragma unroll
    for (int i = 0; i < 10; ++i) acc[i] = 0.f;

#pragma unroll 8
    for (int kk = 0; kk < KW; ++kk) {
        const float wv = W1p[(size_t)(k0 + kk) * CD + c];
#pragma unroll
        for (int i = 0; i < 10; ++i)
            acc[i] = fmaf(s_src[i][kk], wv, acc[i]);
    }
#pragma unroll
    for (int i = 0; i < 10; ++i)
        if (i < nrows) dst[(size_t)i * CD + c] = acc[i];

    // ---- last-finisher reduction for this (x,y) tile ----
    __syncthreads();                       // all partial stores drained (vmcnt0)
    if (threadIdx.x == 0) {
        __threadfence();                   // release: partials visible device-wide
        const unsigned old = atomicAdd(&g_cnt[blockIdx.y * 4 + blockIdx.x], 1u);
        s_last = ((old & 15u) == 15u);     // 16th arrival this call
    }
    __syncthreads();
    if (s_last) {
        __threadfence();                   // acquire: see other blocks' partials
        if (is_ctx) {
            for (int r = 0; r < BD; ++r) {
                float v = b1[c];
#pragma unroll
                for (int kz2 = 0; kz2 < KS; ++kz2) v += g_pctx[kz2][r][c];
                g_ctxb[r][c] = v;
            }
        } else {
            for (int r = 0; r < 10; ++r) {
                const int p = ych * 10 + r;
                float v = 0.f;
#pragma unroll
                for (int kz2 = 0; kz2 < KS; ++kz2) v += g_ptrg[kz2][p][c];
                g_trgh[p][c] = v;
            }
        }
    }
}

// -------- K2: per-pattern score from final sums (light) ---------------------
// grid = (PD), block 512: wave w handles batch row b=w.
__global__ __launch_bounds__(512) void score_kernel(const float* __restrict__ W2,
                                                    const float* __restrict__ b2,
                                                    const float* __restrict__ conf) {
    const int p = blockIdx.x;
    __shared__ float s_logit[BD];

    const int b = threadIdx.x >> 6, lane = threadIdx.x & 63;
    float sum = 0.f;
    for (int c = lane; c < CD; c += 64) {
        const float v = g_trgh[p][c] + g_ctxb[b][c];
        sum = fmaf(fmaxf(v, 0.f), W2[c], sum);
    }
#pragma unroll
    for (int off = 32; off > 0; off >>= 1) sum += __shfl_down(sum, off);
    if (lane == 0) s_logit[b] = sum + b2[0];
    __syncthreads();
    if (threadIdx.x == 0) {
        float s = 0.f;
#pragma unroll
        for (int bb = 0; bb < BD; ++bb) s += 1.f / (1.f + expf(-s_logit[bb]));
        s *= (1.f / BD);
        g_wd[p] = (s > SIM_THR) ? s * conf[p] * LAMBDA : 0.f;
    }
}

// -------- K3: out = attn + sum_t w[t]*biases[idx[t]]  (R11 verbatim) --------
__global__ __launch_bounds__(256) void out_kernel(const float* __restrict__ attn,
                                                  const float* __restrict__ biases,
                                                  float* __restrict__ out) {
    __shared__ float    s_w[PD];
    __shared__ unsigned s_off[PD];
    __shared__ int      s_n;
    __shared__ float    s_part[4][SEG];     // 32 KB

    if (threadIdx.x < 64) {                 // wave 0: parallel compaction
        const int lane = threadIdx.x;
        const float w0 = g_wd[lane];
        const float w1 = (lane < PD - 64) ? g_wd[lane + 64] : 0.f;
        const unsigned long long m0 = __ballot(w0 != 0.f);
        const unsigned long long m1 = __ballot(w1 != 0.f);
        const unsigned long long below = (1ull << lane) - 1;
        const int c0 = __popcll(m0);
        if (w0 != 0.f) {
            const int i = __popcll(m0 & below);
            s_w[i] = w0; s_off[i] = (unsigned)(lane * TT);
        }
        if (w1 != 0.f) {
            const int i = c0 + __popcll(m1 & below);
            s_w[i] = w1; s_off[i] = (unsigned)((lane + 64) * TT);
        }
        if (lane == 0) s_n = c0 + __popcll(m1);
    }
    __syncthreads();
    const int n = s_n;

    const int wv = threadIdx.x >> 6, lane = threadIdx.x & 63;
    const size_t seg = (size_t)blockIdx.x * SEG;

    f4 acc[8];
#pragma unroll
    for (int j = 0; j < 8; ++j) acc[j] = (f4){0.f, 0.f, 0.f, 0.f};

    for (int t = wv; t < n; t += 4) {
        const float w = s_w[t];
        const float* bp = biases + (size_t)s_off[t] + seg + (size_t)lane * 4;
        f4 v[8];
        if (s_off[t] < (unsigned)(SPLITQ * TT)) {       // wave-uniform branch
#pragma unroll
            for (int j = 0; j < 8; ++j) v[j] = *(const f4*)(bp + j * 256);
        } else {
#pragma unroll
            for (int j = 0; j < 8; ++j)
                v[j] = __builtin_nontemporal_load((const f4*)(bp + j * 256));
        }
#pragma unroll
        for (int j = 0; j < 8; ++j) {
            acc[j].x = fmaf(w, v[j].x, acc[j].x);
            acc[j].y = fmaf(w, v[j].y, acc[j].y);
            acc[j].z = fmaf(w, v[j].z, acc[j].z);
            acc[j].w = fmaf(w, v[j].w, acc[j].w);
        }
    }

#pragma unroll
    for (int j = 0; j < 8; ++j)
        *(f4*)&s_part[wv][j * 256 + lane * 4] = acc[j];
    __syncthreads();

    const int e = threadIdx.x * 8;
    f4 r0 = (f4){0.f, 0.f, 0.f, 0.f}, r1 = r0;
#pragma unroll
    for (int w2 = 0; w2 < 4; ++w2) {
        r0 += *(const f4*)&s_part[w2][e];
        r1 += *(const f4*)&s_part[w2][e + 4];
    }

#pragma unroll
    for (int b = 0; b < BD; ++b) {
        const size_t off = (size_t)b * TT + seg + (size_t)e;
        const f4 a0 = *(const f4*)(attn + off);
        const f4 a1 = *(const f4*)(attn + off + 4);
        __builtin_nontemporal_store(a0 + r0, (f4*)(out + off));
        __builtin_nontemporal_store(a1 + r1, (f4*)(out + off + 4));
    }
}

extern "C" void kernel_launch(void* const* d_in, const int* in_sizes, int n_in,
                              void* d_out, int out_size, void* d_ws, size_t ws_size,
                              hipStream_t stream) {
    const float* attn     = (const float*)d_in[0];  // (B,T,T)
    const float* context  = (const float*)d_in[1];  // (B,C)
    const float* triggers = (const float*)d_in[2];  // (P,C)
    const float* biases   = (const float*)d_in[3];  // (P,T,T)
    const float* conf     = (const float*)d_in[4];  // (P,)
    const float* W1       = (const float*)d_in[5];  // (2C,C)
    const float* b1       = (const float*)d_in[6];  // (C,)
    const float* W2       = (const float*)d_in[7];  // (C,)
    const float* b2       = (const float*)d_in[8];  // (1,)
    float* out = (float*)d_out;

    hipLaunchKernelGGL(hidden_kernel, dim3(4, 11, KS), dim3(256), 0, stream,
                       context, triggers, W1, b1);
    hipLaunchKernelGGL(score_kernel, dim3(PD), dim3(512), 0, stream, W2, b2, conf);
    hipLaunchKernelGGL(out_kernel, dim3(TT / SEG), dim3(256), 0, stream, attn, biases, out);
}

// Round 14
// 99.237 us; speedup vs baseline: 1.3209x; 1.3209x over previous
//
#include <hip/hip_runtime.h>
#include <hip/hip_bf16.h>
#include <math.h>

#define BD 8        // batch
#define TD 1024     // T
#define CD 1024     // C
#define PD 100      // patterns
#define KS 16       // K-split for hidden GEMMs
#define KW (CD / KS)   // 64
#define SEG 2048    // floats per out-block segment (8 KB)
#define TT (TD * TD)
#define SPLITQ 48   // planes q < SPLITQ load cacheable (as R11)
#define LAMBDA 0.1f
#define SIM_THR 0.5f

typedef float f4 __attribute__((ext_vector_type(4)));

// -------- device-global scratch (fully rewritten each call; deterministic) --
__device__ float g_pctx[KS][BD][CD];   // k-partials of context hidden
__device__ float g_ptrg[KS][PD][CD];   // k-partials of trigger hidden
__device__ float g_ctxb[BD][CD];       // b1 + sum_kz pctx  (final)
__device__ float g_trgh[PD][CD];       // sum_kz ptrg       (final)
__device__ float g_wd[PD];             // dense gated weights, lambda folded in

// -------- K1: partial hidden = X @ W1part over a 64-wide K slice -----------
// grid = (CD/256, 11, KS): y==0 -> context (8 rows), y=1..10 -> trigger chunk
__global__ __launch_bounds__(256) void hidden_kernel(const float* __restrict__ context,
                                                     const float* __restrict__ triggers,
                                                     const float* __restrict__ W1) {
    const int c  = blockIdx.x * 256 + threadIdx.x;   // output column
    const int kz = blockIdx.z;
    const int k0 = kz * KW;
    const bool is_ctx = (blockIdx.y == 0);
    const int  ych = blockIdx.y - 1;                 // trigger chunk 0..9
    const float* __restrict__ W1p = is_ctx ? W1 : (W1 + (size_t)CD * CD);
    const float* __restrict__ src = is_ctx ? context : (triggers + (size_t)ych * 10 * CD);
    float* __restrict__ dst = is_ctx ? &g_pctx[kz][0][0] : &g_ptrg[kz][ych * 10][0];
    const int nrows = is_ctx ? 8 : 10;

    __shared__ float s_src[10][KW];
    for (int t = threadIdx.x; t < 10 * KW; t += 256) {
        const int r = t >> 6, k = t & (KW - 1);
        s_src[r][k] = src[(size_t)(r < nrows ? r : 0) * CD + k0 + k];
    }
    __syncthreads();

    float acc[10];
#pragma unroll
    for (int i = 0; i < 10; ++i) acc[i] = 0.f;

#pragma unroll 8
    for (int kk = 0; kk < KW; ++kk) {
        const float wv = W1p[(size_t)(k0 + kk) * CD + c];
#pragma unroll
        for (int i = 0; i < 10; ++i)
            acc[i] = fmaf(s_src[i][kk], wv, acc[i]);
    }
#pragma unroll
    for (int i = 0; i < 10; ++i)
        if (i < nrows) dst[(size_t)i * CD + c] = acc[i];
}

// -------- K2: final sums — ctx rows (+b1) and trigger rows ------------------
// grid = (32 + 400): blocks 0..31 -> g_ctxb (8x1024), 32..431 -> g_trgh.
__global__ __launch_bounds__(256) void sum_kernel(const float* __restrict__ b1) {
    if (blockIdx.x < 32) {
        const int idx = blockIdx.x * 256 + threadIdx.x;   // 0..8191
        const int b = idx >> 10, c = idx & (CD - 1);
        float v = b1[c];
#pragma unroll
        for (int kz = 0; kz < KS; ++kz) v += g_pctx[kz][b][c];
        g_ctxb[b][c] = v;
    } else {
        const int idx = (blockIdx.x - 32) * 256 + threadIdx.x;  // 0..102399
        const int p = idx >> 10, c = idx & (CD - 1);
        float v = 0.f;
#pragma unroll
        for (int kz = 0; kz < KS; ++kz) v += g_ptrg[kz][p][c];
        g_trgh[p][c] = v;
    }
}

// -------- K3: per-pattern score from final sums (light) ---------------------
// grid = (PD), block 512: wave w handles batch row b=w.
__global__ __launch_bounds__(512) void score_kernel(const float* __restrict__ W2,
                                                    const float* __restrict__ b2,
                                                    const float* __restrict__ conf) {
    const int p = blockIdx.x;
    __shared__ float s_logit[BD];

    const int b = threadIdx.x >> 6, lane = threadIdx.x & 63;
    float sum = 0.f;
    for (int c = lane; c < CD; c += 64) {
        const float v = g_trgh[p][c] + g_ctxb[b][c];
        sum = fmaf(fmaxf(v, 0.f), W2[c], sum);
    }
#pragma unroll
    for (int off = 32; off > 0; off >>= 1) sum += __shfl_down(sum, off);
    if (lane == 0) s_logit[b] = sum + b2[0];
    __syncthreads();
    if (threadIdx.x == 0) {
        float s = 0.f;
#pragma unroll
        for (int bb = 0; bb < BD; ++bb) s += 1.f / (1.f + expf(-s_logit[bb]));
        s *= (1.f / BD);
        g_wd[p] = (s > SIM_THR) ? s * conf[p] * LAMBDA : 0.f;
    }
}

// -------- K4: out = attn + sum_t w[t]*biases[idx[t]]  (R11 verbatim) --------
__global__ __launch_bounds__(256) void out_kernel(const float* __restrict__ attn,
                                                  const float* __restrict__ biases,
                                                  float* __restrict__ out) {
    __shared__ float    s_w[PD];
    __shared__ unsigned s_off[PD];
    __shared__ int      s_n;
    __shared__ float    s_part[4][SEG];     // 32 KB

    if (threadIdx.x < 64) {                 // wave 0: parallel compaction
        const int lane = threadIdx.x;
        const float w0 = g_wd[lane];
        const float w1 = (lane < PD - 64) ? g_wd[lane + 64] : 0.f;
        const unsigned long long m0 = __ballot(w0 != 0.f);
        const unsigned long long m1 = __ballot(w1 != 0.f);
        const unsigned long long below = (1ull << lane) - 1;
        const int c0 = __popcll(m0);
        if (w0 != 0.f) {
            const int i = __popcll(m0 & below);
            s_w[i] = w0; s_off[i] = (unsigned)(lane * TT);
        }
        if (w1 != 0.f) {
            const int i = c0 + __popcll(m1 & below);
            s_w[i] = w1; s_off[i] = (unsigned)((lane + 64) * TT);
        }
        if (lane == 0) s_n = c0 + __popcll(m1);
    }
    __syncthreads();
    const int n = s_n;

    const int wv = threadIdx.x >> 6, lane = threadIdx.x & 63;
    const size_t seg = (size_t)blockIdx.x * SEG;

    f4 acc[8];
#pragma unroll
    for (int j = 0; j < 8; ++j) acc[j] = (f4){0.f, 0.f, 0.f, 0.f};

    for (int t = wv; t < n; t += 4) {
        const float w = s_w[t];
        const float* bp = biases + (size_t)s_off[t] + seg + (size_t)lane * 4;
        f4 v[8];
        if (s_off[t] < (unsigned)(SPLITQ * TT)) {       // wave-uniform branch
#pragma unroll
            for (int j = 0; j < 8; ++j) v[j] = *(const f4*)(bp + j * 256);
        } else {
#pragma unroll
            for (int j = 0; j < 8; ++j)
                v[j] = __builtin_nontemporal_load((const f4*)(bp + j * 256));
        }
#pragma unroll
        for (int j = 0; j < 8; ++j) {
            acc[j].x = fmaf(w, v[j].x, acc[j].x);
            acc[j].y = fmaf(w, v[j].y, acc[j].y);
            acc[j].z = fmaf(w, v[j].z, acc[j].z);
            acc[j].w = fmaf(w, v[j].w, acc[j].w);
        }
    }

#pragma unroll
    for (int j = 0; j < 8; ++j)
        *(f4*)&s_part[wv][j * 256 + lane * 4] = acc[j];
    __syncthreads();

    const int e = threadIdx.x * 8;
    f4 r0 = (f4){0.f, 0.f, 0.f, 0.f}, r1 = r0;
#pragma unroll
    for (int w2 = 0; w2 < 4; ++w2) {
        r0 += *(const f4*)&s_part[w2][e];
        r1 += *(const f4*)&s_part[w2][e + 4];
    }

#pragma unroll
    for (int b = 0; b < BD; ++b) {
        const size_t off = (size_t)b * TT + seg + (size_t)e;
        const f4 a0 = *(const f4*)(attn + off);
        const f4 a1 = *(const f4*)(attn + off + 4);
        __builtin_nontemporal_store(a0 + r0, (f4*)(out + off));
        __builtin_nontemporal_store(a1 + r1, (f4*)(out + off + 4));
    }
}

extern "C" void kernel_launch(void* const* d_in, const int* in_sizes, int n_in,
                              void* d_out, int out_size, void* d_ws, size_t ws_size,
                              hipStream_t stream) {
    const float* attn     = (const float*)d_in[0];  // (B,T,T)
    const float* context  = (const float*)d_in[1];  // (B,C)
    const float* triggers = (const float*)d_in[2];  // (P,C)
    const float* biases   = (const float*)d_in[3];  // (P,T,T)
    const float* conf     = (const float*)d_in[4];  // (P,)
    const float* W1       = (const float*)d_in[5];  // (2C,C)
    const float* b1       = (const float*)d_in[6];  // (C,)
    const float* W2       = (const float*)d_in[7];  // (C,)
    const float* b2       = (const float*)d_in[8];  // (1,)
    float* out = (float*)d_out;

    hipLaunchKernelGGL(hidden_kernel, dim3(CD / 256, 11, KS), dim3(256), 0, stream,
                       context, triggers, W1);
    hipLaunchKernelGGL(sum_kernel, dim3(32 + 400), dim3(256), 0, stream, b1);
    hipLaunchKernelGGL(score_kernel, dim3(PD), dim3(512), 0, stream, W2, b2, conf);
    hipLaunchKernelGGL(out_kernel, dim3(TT / SEG), dim3(256), 0, stream, attn, biases, out);
}

// Round 15
// 95.851 us; speedup vs baseline: 1.3676x; 1.0353x over previous
//
#include <hip/hip_runtime.h>
#include <hip/hip_bf16.h>
#include <math.h>

#define BD 8        // batch
#define TD 1024     // T
#define CD 1024     // C
#define PD 100      // patterns
#define KS 16       // K-split for hidden GEMMs
#define KW (CD / KS)   // 64
#define TT (TD * TD)
#define LAMBDA 0.1f
#define SIM_THR 0.5f

typedef float f4 __attribute__((ext_vector_type(4)));

// -------- device-global scratch (fully rewritten each call; deterministic) --
__device__ float g_pctx[KS][BD][CD];   // k-partials of context hidden
__device__ float g_ptrg[KS][PD][CD];   // k-partials of trigger hidden
__device__ float g_ctxb[BD][CD];       // b1 + sum_kz pctx  (final)
__device__ float g_trgh[PD][CD];       // sum_kz ptrg       (final)
__device__ float g_wd[PD];             // dense gated weights, lambda folded in

// -------- K1: partial hidden = X @ W1part over a 64-wide K slice -----------
// grid = (CD/256, 11, KS): y==0 -> context (8 rows), y=1..10 -> trigger chunk
__global__ __launch_bounds__(256) void hidden_kernel(const float* __restrict__ context,
                                                     const float* __restrict__ triggers,
                                                     const float* __restrict__ W1) {
    const int c  = blockIdx.x * 256 + threadIdx.x;   // output column
    const int kz = blockIdx.z;
    const int k0 = kz * KW;
    const bool is_ctx = (blockIdx.y == 0);
    const int  ych = blockIdx.y - 1;                 // trigger chunk 0..9
    const float* __restrict__ W1p = is_ctx ? W1 : (W1 + (size_t)CD * CD);
    const float* __restrict__ src = is_ctx ? context : (triggers + (size_t)ych * 10 * CD);
    float* __restrict__ dst = is_ctx ? &g_pctx[kz][0][0] : &g_ptrg[kz][ych * 10][0];
    const int nrows = is_ctx ? 8 : 10;

    __shared__ float s_src[10][KW];
    for (int t = threadIdx.x; t < 10 * KW; t += 256) {
        const int r = t >> 6, k = t & (KW - 1);
        s_src[r][k] = src[(size_t)(r < nrows ? r : 0) * CD + k0 + k];
    }
    __syncthreads();

    float acc[10];
#pragma unroll
    for (int i = 0; i < 10; ++i) acc[i] = 0.f;

#pragma unroll 8
    for (int kk = 0; kk < KW; ++kk) {
        const float wv = W1p[(size_t)(k0 + kk) * CD + c];
#pragma unroll
        for (int i = 0; i < 10; ++i)
            acc[i] = fmaf(s_src[i][kk], wv, acc[i]);
    }
#pragma unroll
    for (int i = 0; i < 10; ++i)
        if (i < nrows) dst[(size_t)i * CD + c] = acc[i];
}

// -------- K2: final sums — ctx rows (+b1) and trigger rows ------------------
// grid = (32 + 400): blocks 0..31 -> g_ctxb (8x1024), 32..431 -> g_trgh.
__global__ __launch_bounds__(256) void sum_kernel(const float* __restrict__ b1) {
    if (blockIdx.x < 32) {
        const int idx = blockIdx.x * 256 + threadIdx.x;   // 0..8191
        const int b = idx >> 10, c = idx & (CD - 1);
        float v = b1[c];
#pragma unroll
        for (int kz = 0; kz < KS; ++kz) v += g_pctx[kz][b][c];
        g_ctxb[b][c] = v;
    } else {
        const int idx = (blockIdx.x - 32) * 256 + threadIdx.x;  // 0..102399
        const int p = idx >> 10, c = idx & (CD - 1);
        float v = 0.f;
#pragma unroll
        for (int kz = 0; kz < KS; ++kz) v += g_ptrg[kz][p][c];
        g_trgh[p][c] = v;
    }
}

// -------- K3: per-pattern score from final sums (light) ---------------------
// grid = (PD), block 512: wave w handles batch row b=w.
__global__ __launch_bounds__(512) void score_kernel(const float* __restrict__ W2,
                                                    const float* __restrict__ b2,
                                                    const float* __restrict__ conf) {
    const int p = blockIdx.x;
    __shared__ float s_logit[BD];

    const int b = threadIdx.x >> 6, lane = threadIdx.x & 63;
    float sum = 0.f;
    for (int c = lane; c < CD; c += 64) {
        const float v = g_trgh[p][c] + g_ctxb[b][c];
        sum = fmaf(fmaxf(v, 0.f), W2[c], sum);
    }
#pragma unroll
    for (int off = 32; off > 0; off >>= 1) sum += __shfl_down(sum, off);
    if (lane == 0) s_logit[b] = sum + b2[0];
    __syncthreads();
    if (threadIdx.x == 0) {
        float s = 0.f;
#pragma unroll
        for (int bb = 0; bb < BD; ++bb) s += 1.f / (1.f + expf(-s_logit[bb]));
        s *= (1.f / BD);
        g_wd[p] = (s > SIM_THR) ? s * conf[p] * LAMBDA : 0.f;
    }
}

// -------- K4: out = attn + sum_t w[t]*biases[idx[t]]  (pattern-innermost) ---
// grid = (1024) x 256 thr: thread owns one f4 of the (T,T) plane; 8-deep
// pattern unroll; cacheable loads; nontemporal stores; ballot compaction.
__global__ __launch_bounds__(256) void out_kernel(const float* __restrict__ attn,
                                                  const float* __restrict__ biases,
                                                  float* __restrict__ out) {
    __shared__ float    s_w[PD];
    __shared__ unsigned s_off[PD];
    __shared__ int      s_n;

    if (threadIdx.x < 64) {                 // wave 0: parallel compaction
        const int lane = threadIdx.x;
        const float w0 = g_wd[lane];
        const float w1 = (lane < PD - 64) ? g_wd[lane + 64] : 0.f;
        const unsigned long long m0 = __ballot(w0 != 0.f);
        const unsigned long long m1 = __ballot(w1 != 0.f);
        const unsigned long long below = (1ull << lane) - 1;
        const int c0 = __popcll(m0);
        if (w0 != 0.f) {
            const int i = __popcll(m0 & below);
            s_w[i] = w0; s_off[i] = (unsigned)(lane * TT);
        }
        if (w1 != 0.f) {
            const int i = c0 + __popcll(m1 & below);
            s_w[i] = w1; s_off[i] = (unsigned)((lane + 64) * TT);
        }
        if (lane == 0) s_n = c0 + __popcll(m1);
    }
    __syncthreads();
    const int n = s_n;

    const size_t seg = (size_t)blockIdx.x * 1024 + (size_t)threadIdx.x * 4;

    f4 acc = {0.f, 0.f, 0.f, 0.f};
    int t = 0;
    for (; t + 8 <= n; t += 8) {
        float w[8];
        f4 v[8];
#pragma unroll
        for (int u = 0; u < 8; ++u) w[u] = s_w[t + u];
#pragma unroll
        for (int u = 0; u < 8; ++u)
            v[u] = *(const f4*)(biases + (size_t)s_off[t + u] + seg);
#pragma unroll
        for (int u = 0; u < 8; ++u) {
            acc.x = fmaf(w[u], v[u].x, acc.x);
            acc.y = fmaf(w[u], v[u].y, acc.y);
            acc.z = fmaf(w[u], v[u].z, acc.z);
            acc.w = fmaf(w[u], v[u].w, acc.w);
        }
    }
    for (; t < n; ++t) {
        const float w = s_w[t];
        const f4 bv = *(const f4*)(biases + (size_t)s_off[t] + seg);
        acc.x = fmaf(w, bv.x, acc.x);
        acc.y = fmaf(w, bv.y, acc.y);
        acc.z = fmaf(w, bv.z, acc.z);
        acc.w = fmaf(w, bv.w, acc.w);
    }

#pragma unroll
    for (int b = 0; b < BD; ++b) {
        const size_t off = (size_t)b * TT + seg;
        const f4 av = *(const f4*)(attn + off);
        __builtin_nontemporal_store(av + acc, (f4*)(out + off));
    }
}

extern "C" void kernel_launch(void* const* d_in, const int* in_sizes, int n_in,
                              void* d_out, int out_size, void* d_ws, size_t ws_size,
                              hipStream_t stream) {
    const float* attn     = (const float*)d_in[0];  // (B,T,T)
    const float* context  = (const float*)d_in[1];  // (B,C)
    const float* triggers = (const float*)d_in[2];  // (P,C)
    const float* biases   = (const float*)d_in[3];  // (P,T,T)
    const float* conf     = (const float*)d_in[4];  // (P,)
    const float* W1       = (const float*)d_in[5];  // (2C,C)
    const float* b1       = (const float*)d_in[6];  // (C,)
    const float* W2       = (const float*)d_in[7];  // (C,)
    const float* b2       = (const float*)d_in[8];  // (1,)
    float* out = (float*)d_out;

    hipLaunchKernelGGL(hidden_kernel, dim3(CD / 256, 11, KS), dim3(256), 0, stream,
                       context, triggers, W1);
    hipLaunchKernelGGL(sum_kernel, dim3(32 + 400), dim3(256), 0, stream, b1);
    hipLaunchKernelGGL(score_kernel, dim3(PD), dim3(512), 0, stream, W2, b2, conf);
    hipLaunchKernelGGL(out_kernel, dim3(TT / 1024), dim3(256), 0, stream, attn, biases, out);
}